// Round 5
// baseline (1277.570 us; speedup 1.0000x reference)
//
#include <hip/hip_runtime.h>

#define DEVINL __device__ __forceinline__

typedef __bf16 bf16x8 __attribute__((ext_vector_type(8)));
typedef float  f32x4  __attribute__((ext_vector_type(4)));

DEVINL unsigned short f2bf(float f) {
  union { float f; unsigned int u; } v; v.f = f;
  unsigned int u = v.u;
  return (unsigned short)((u + 0x7fffu + ((u >> 16) & 1u)) >> 16);
}
DEVINL float bf2f(unsigned short b) {
  union { unsigned int u; float f; } v; v.u = ((unsigned int)b) << 16;
  return v.f;
}

#define GLD_LDS16(SRC, DST) \
  __builtin_amdgcn_global_load_lds((const __attribute__((address_space(1))) void*)(SRC), \
                                   (__attribute__((address_space(3))) void*)(DST), 16, 0, 0)

// ---------------------------------------------------------------------------
// Plain bf16 GEMM: C[M,N] = A[M,K] * B[N,K]^T
// EPI: 2=bf16 transposed store (LDS-transposed, coalesced),
//      3=f32 store + res, 4=bf16 relu(x+bias), 5=f32 x+bias+res
// ---------------------------------------------------------------------------
template<int EPI>
__global__ __launch_bounds__(256) void gemm_bt(
    const unsigned short* __restrict__ Ap, const unsigned short* __restrict__ Bp, void* __restrict__ Cp,
    const float* __restrict__ bias, const float* __restrict__ res,
    int M, int N, int K, int lda, int ldb, int ldc, int H,
    long sAb, long sAh, long sBb, long sBh, long sCb, long sCh)
{
  constexpr int SMEMSZ = (EPI == 2) ? 34816 : 16384;
  __shared__ __align__(16) char smem[SMEMSZ];
  unsigned short* sB = (unsigned short*)(smem + 8192);

  const int tid = threadIdx.x;
  const int w = tid >> 6, l = tid & 63;
  const int wr = w >> 1, wc = w & 1;
  const int ntn = N >> 7;
  const int tm = (int)blockIdx.x / ntn;
  const int tn = (int)blockIdx.x - tm * ntn;
  const int z = blockIdx.z;
  const int bb = z / H, hh = z - bb * H;
  const long offA = (long)bb * sAb + (long)hh * sAh;
  const long offB = (long)bb * sBb + (long)hh * sBh;
  const long offC = (long)bb * sCb + (long)hh * sCh;

  f32x4 zero = {0.f, 0.f, 0.f, 0.f};
  f32x4 acc[4][4];
  #pragma unroll
  for (int m = 0; m < 4; ++m)
    #pragma unroll
    for (int n = 0; n < 4; ++n) acc[m][n] = zero;

  for (int k0 = 0; k0 < K; k0 += 32) {
    __syncthreads();
    const int rl = l >> 2, cl = (l & 3) << 3;
    #pragma unroll
    for (int i = 0; i < 2; ++i) {
      const unsigned short* srcA = Ap + offA + (long)(tm*128 + w*32 + i*16 + rl) * lda + (k0 + cl);
      GLD_LDS16(srcA, (unsigned short*)smem + (w*32 + i*16) * 32);
      const unsigned short* srcB = Bp + offB + (long)(tn*128 + w*32 + i*16 + rl) * ldb + (k0 + cl);
      GLD_LDS16(srcB, sB + (w*32 + i*16) * 32);
    }
    __syncthreads();

    bf16x8 af[4], bfr[4];
    const unsigned short* sA = (const unsigned short*)smem;
    #pragma unroll
    for (int m = 0; m < 4; ++m) {
      int row = wr*64 + m*16 + (l & 15);
      af[m] = *(const bf16x8*)(sA + row*32 + ((l >> 4) << 3));
    }
    #pragma unroll
    for (int n = 0; n < 4; ++n) {
      int row = wc*64 + n*16 + (l & 15);
      bfr[n] = *(const bf16x8*)(sB + row*32 + ((l >> 4) << 3));
    }
    #pragma unroll
    for (int m = 0; m < 4; ++m)
      #pragma unroll
      for (int n = 0; n < 4; ++n)
        acc[m][n] = __builtin_amdgcn_mfma_f32_16x16x32_bf16(af[m], bfr[n], acc[m][n], 0, 0, 0);
  }

  if constexpr (EPI == 2) {
    __syncthreads();
    unsigned short* sT = (unsigned short*)smem;
    #pragma unroll
    for (int m = 0; m < 4; ++m)
      #pragma unroll
      for (int n = 0; n < 4; ++n)
        #pragma unroll
        for (int r = 0; r < 4; ++r) {
          int rowl = wr*64 + m*16 + ((l >> 4) << 2) + r;
          int coll = wc*64 + n*16 + (l & 15);
          sT[coll*136 + rowl] = f2bf(acc[m][n][r]);
        }
    __syncthreads();
    #pragma unroll
    for (int i = 0; i < 8; ++i) {
      int idx = tid + i*256;
      int c = idx >> 4, ch = idx & 15;
      bf16x8 vv = *(const bf16x8*)(sT + c*136 + ch*8);
      *(bf16x8*)((unsigned short*)Cp + offC + (long)(tn*128 + c)*ldc + (tm*128 + ch*8)) = vv;
    }
  } else {
    #pragma unroll
    for (int m = 0; m < 4; ++m) {
      #pragma unroll
      for (int n = 0; n < 4; ++n) {
        #pragma unroll
        for (int r = 0; r < 4; ++r) {
          int row = tm*128 + wr*64 + m*16 + ((l >> 4) << 2) + r;
          int col = tn*128 + wc*64 + n*16 + (l & 15);
          float v = acc[m][n][r];
          long ci = offC + (long)row * ldc + col;
          if constexpr (EPI == 3) {
            ((float*)Cp)[ci] = v + res[ci];
          } else if constexpr (EPI == 4) {
            ((unsigned short*)Cp)[ci] = f2bf(fmaxf(v + bias[col], 0.f));
          } else if constexpr (EPI == 5) {
            ((float*)Cp)[ci] = v + bias[col] + res[ci];
          }
        }
      }
    }
  }
}

// ---------------------------------------------------------------------------
// Fused split-precision GEMM: C = (A1+A2)*(B1+B2)^T (dropping A2*B2),
// split-bf16 output (hi->Cp, lo->Cp2).
// ---------------------------------------------------------------------------
__global__ __launch_bounds__(256) void gemm_split(
    const unsigned short* __restrict__ A1, const unsigned short* __restrict__ A2,
    const unsigned short* __restrict__ B1, const unsigned short* __restrict__ B2,
    unsigned short* __restrict__ Cp, unsigned short* __restrict__ Cp2,
    int M, int N, int K, int lda, int ldb, int ldc)
{
  __shared__ __align__(16) unsigned short sAll[4 * 4096];
  unsigned short* sA1 = sAll;
  unsigned short* sA2 = sAll + 4096;
  unsigned short* sB1 = sAll + 8192;
  unsigned short* sB2 = sAll + 12288;

  const int tid = threadIdx.x;
  const int w = tid >> 6, l = tid & 63;
  const int wr = w >> 1, wc = w & 1;
  const int ntn = N >> 7;
  const int tm = (int)blockIdx.x / ntn;
  const int tn = (int)blockIdx.x - tm * ntn;

  f32x4 zero = {0.f, 0.f, 0.f, 0.f};
  f32x4 acc[4][4];
  #pragma unroll
  for (int m = 0; m < 4; ++m)
    #pragma unroll
    for (int n = 0; n < 4; ++n) acc[m][n] = zero;

  const int rl = l >> 2, cl = (l & 3) << 3;

  for (int k0 = 0; k0 < K; k0 += 32) {
    __syncthreads();
    #pragma unroll
    for (int i = 0; i < 2; ++i) {
      const int row = w*32 + i*16;
      const long asrc = (long)(tm*128 + row + rl) * lda + (k0 + cl);
      const long bsrc = (long)(tn*128 + row + rl) * ldb + (k0 + cl);
      GLD_LDS16(A1 + asrc, sA1 + row*32);
      GLD_LDS16(A2 + asrc, sA2 + row*32);
      GLD_LDS16(B1 + bsrc, sB1 + row*32);
      GLD_LDS16(B2 + bsrc, sB2 + row*32);
    }
    __syncthreads();

    bf16x8 a1[4], a2[4], bb4[4];
    int aoff[4], boff[4];
    #pragma unroll
    for (int m = 0; m < 4; ++m) {
      int row = wr*64 + m*16 + (l & 15);
      aoff[m] = row*32 + ((l >> 4) << 3);
      a1[m] = *(const bf16x8*)(sA1 + aoff[m]);
      a2[m] = *(const bf16x8*)(sA2 + aoff[m]);
    }
    #pragma unroll
    for (int n = 0; n < 4; ++n) {
      int row = wc*64 + n*16 + (l & 15);
      boff[n] = row*32 + ((l >> 4) << 3);
      bb4[n] = *(const bf16x8*)(sB1 + boff[n]);
    }
    #pragma unroll
    for (int m = 0; m < 4; ++m)
      #pragma unroll
      for (int n = 0; n < 4; ++n) {
        acc[m][n] = __builtin_amdgcn_mfma_f32_16x16x32_bf16(a1[m], bb4[n], acc[m][n], 0, 0, 0);
        acc[m][n] = __builtin_amdgcn_mfma_f32_16x16x32_bf16(a2[m], bb4[n], acc[m][n], 0, 0, 0);
      }
    #pragma unroll
    for (int n = 0; n < 4; ++n)
      bb4[n] = *(const bf16x8*)(sB2 + boff[n]);
    #pragma unroll
    for (int m = 0; m < 4; ++m)
      #pragma unroll
      for (int n = 0; n < 4; ++n)
        acc[m][n] = __builtin_amdgcn_mfma_f32_16x16x32_bf16(a1[m], bb4[n], acc[m][n], 0, 0, 0);
  }

  #pragma unroll
  for (int m = 0; m < 4; ++m) {
    #pragma unroll
    for (int n = 0; n < 4; ++n) {
      #pragma unroll
      for (int r = 0; r < 4; ++r) {
        int row = tm*128 + wr*64 + m*16 + ((l >> 4) << 2) + r;
        int col = tn*128 + wc*64 + n*16 + (l & 15);
        float v = acc[m][n][r];
        long ci = (long)row * ldc + col;
        unsigned short hv = f2bf(v);
        Cp[ci] = hv;
        Cp2[ci] = f2bf(v - bf2f(hv));
      }
    }
  }
}

// ---------------------------------------------------------------------------
// Fused attention v3: logits (split-bf16) + mask + softmax + attn store + PV.
// Block = (b, h, 32 q-rows); 4 waves (256 thr). Wave w owns key-quarter
// [w*256, +256) for logits (mf=2 rows), and d-slice [w*32, +32) for PV.
// P staged bf16 in ONE 32 KB half-buffer, two passes:
//   half A = each wave's keys [w*256, +128)  -> buf col w*128 + nf*16+l15
//   half B = each wave's keys [w*256+128, +128)
// PV key remap: buf col c -> true key (c>>7)*256 + keyoff + (c&127).
// ---------------------------------------------------------------------------
__global__ __launch_bounds__(256, 4) void attn_fused(
    const unsigned short* __restrict__ q1, const unsigned short* __restrict__ q2,
    const unsigned short* __restrict__ kn1, const unsigned short* __restrict__ kn2,
    const unsigned short* __restrict__ vt, const unsigned int* __restrict__ mbits,
    float* __restrict__ attn, unsigned short* __restrict__ outm)
{
  __shared__ __align__(16) char smem[33280];   // 32KB P half-buffer + 512B red
  float* red = (float*)(smem + 32768);         // [4 waves][32 rows]

  const int tid = threadIdx.x;
  const int w = tid >> 6, l = tid & 63;
  const int l15 = l & 15, l4 = l >> 4;
  const int row0 = (int)blockIdx.x * 32;
  const int z = (int)blockIdx.z;
  const int bb = z >> 3, hh = z & 7;
  const long base = (long)bb * 1048576;
  const int ocol = hh * 128;

  f32x4 s[2][16];
  #pragma unroll
  for (int mf = 0; mf < 2; ++mf)
    #pragma unroll
    for (int nf = 0; nf < 16; ++nf) s[mf][nf] = (f32x4){0.f, 0.f, 0.f, 0.f};

  // ---- logits: S = q1*kn1 + q2*kn1 + q1*kn2 ----
  #pragma unroll
  for (int ks = 0; ks < 4; ++ks) {
    const int kk = ocol + ks*32 + l4*8;
    bf16x8 a1[2], a2[2];
    #pragma unroll
    for (int mf = 0; mf < 2; ++mf) {
      long ai = base + (long)(row0 + mf*16 + l15) * 1024 + kk;
      a1[mf] = *(const bf16x8*)(q1 + ai);
      a2[mf] = *(const bf16x8*)(q2 + ai);
    }
    #pragma unroll
    for (int nf = 0; nf < 16; ++nf) {
      long bi = base + (long)(w*256 + nf*16 + l15) * 1024 + kk;
      bf16x8 b1 = *(const bf16x8*)(kn1 + bi);
      bf16x8 b2 = *(const bf16x8*)(kn2 + bi);
      #pragma unroll
      for (int mf = 0; mf < 2; ++mf) {
        s[mf][nf] = __builtin_amdgcn_mfma_f32_16x16x32_bf16(a1[mf], b1, s[mf][nf], 0, 0, 0);
        s[mf][nf] = __builtin_amdgcn_mfma_f32_16x16x32_bf16(a2[mf], b1, s[mf][nf], 0, 0, 0);
        s[mf][nf] = __builtin_amdgcn_mfma_f32_16x16x32_bf16(a1[mf], b2, s[mf][nf], 0, 0, 0);
      }
    }
  }

  // ---- mask (bit-packed: word covers 32 keys) ----
  #pragma unroll
  for (int mf = 0; mf < 2; ++mf) {
    #pragma unroll
    for (int r = 0; r < 4; ++r) {
      int mg = row0 + mf*16 + l4*4 + r;
      const unsigned int* wrow = mbits + (long)bb*32768 + (long)mg*32 + w*8;
      unsigned int wd[8];
      #pragma unroll
      for (int j = 0; j < 8; ++j) wd[j] = wrow[j];
      #pragma unroll
      for (int nf = 0; nf < 16; ++nf) {
        unsigned int bit = (wd[nf >> 1] >> (((nf & 1) << 4) + l15)) & 1u;
        if (!bit) s[mf][nf][r] = -1e9f;
      }
    }
  }

  // ---- row max ----
  float mx[2][4];
  #pragma unroll
  for (int mf = 0; mf < 2; ++mf)
    #pragma unroll
    for (int r = 0; r < 4; ++r) {
      float m = s[mf][0][r];
      #pragma unroll
      for (int nf = 1; nf < 16; ++nf) m = fmaxf(m, s[mf][nf][r]);
      #pragma unroll
      for (int o = 1; o < 16; o <<= 1) m = fmaxf(m, __shfl_xor(m, o, 64));
      if (l15 == 0) red[w*32 + mf*16 + l4*4 + r] = m;
    }
  __syncthreads();
  #pragma unroll
  for (int mf = 0; mf < 2; ++mf)
    #pragma unroll
    for (int r = 0; r < 4; ++r) {
      int ml = mf*16 + l4*4 + r;
      mx[mf][r] = fmaxf(fmaxf(red[ml], red[32 + ml]), fmaxf(red[64 + ml], red[96 + ml]));
    }
  __syncthreads();

  // ---- exp + row sum ----
  float sm[2][4];
  #pragma unroll
  for (int mf = 0; mf < 2; ++mf)
    #pragma unroll
    for (int r = 0; r < 4; ++r) sm[mf][r] = 0.f;
  #pragma unroll
  for (int mf = 0; mf < 2; ++mf)
    #pragma unroll
    for (int nf = 0; nf < 16; ++nf)
      #pragma unroll
      for (int r = 0; r < 4; ++r) {
        float e = __expf(s[mf][nf][r] - mx[mf][r]);
        s[mf][nf][r] = e;
        sm[mf][r] += e;
      }
  #pragma unroll
  for (int mf = 0; mf < 2; ++mf)
    #pragma unroll
    for (int r = 0; r < 4; ++r) {
      float t = sm[mf][r];
      #pragma unroll
      for (int o = 1; o < 16; o <<= 1) t += __shfl_xor(t, o, 64);
      if (l15 == 0) red[w*32 + mf*16 + l4*4 + r] = t;
    }
  __syncthreads();
  float inv[2][4];
  #pragma unroll
  for (int mf = 0; mf < 2; ++mf)
    #pragma unroll
    for (int r = 0; r < 4; ++r) {
      int ml = mf*16 + l4*4 + r;
      inv[mf][r] = 1.f / (red[ml] + red[32 + ml] + red[64 + ml] + red[96 + ml]);
    }
  __syncthreads();   // red reads done before P buffer writes

  // ---- normalize + store final attn; stage half A (nf 0..7) ----
  float* arow = attn + (long)(bb*8 + hh) * 1048576;
  #pragma unroll
  for (int mf = 0; mf < 2; ++mf)
    #pragma unroll
    for (int nf = 0; nf < 16; ++nf)
      #pragma unroll
      for (int r = 0; r < 4; ++r) {
        int ml = mf*16 + l4*4 + r;
        float a = s[mf][nf][r] * inv[mf][r];
        s[mf][nf][r] = a;
        arow[(long)(row0 + ml) * 1024 + (w*256 + nf*16 + l15)] = a;
        if (nf < 8) {
          int byte = (ml*1024 + (w*128 + nf*16 + l15)*2) ^ ((ml & 7) << 4);
          *(unsigned short*)(smem + byte) = f2bf(a);
        }
      }
  __syncthreads();

  // ---- PV over a staged half; wave owns d-cols [w*32, +32), all 32 rows ----
  f32x4 o[2][2];
  #pragma unroll
  for (int mf = 0; mf < 2; ++mf)
    #pragma unroll
    for (int df = 0; df < 2; ++df) o[mf][df] = (f32x4){0.f, 0.f, 0.f, 0.f};

  auto pv_half = [&](int keyoff) {
    #pragma unroll
    for (int ks = 0; ks < 16; ++ks) {
      bf16x8 pa[2];
      #pragma unroll
      for (int mf = 0; mf < 2; ++mf) {
        int ml = mf*16 + l15;
        int byte = (ml*1024 + (ks*32 + l4*8)*2) ^ ((ml & 7) << 4);
        pa[mf] = *(const bf16x8*)(smem + byte);
      }
      int kcol = (ks >> 2)*256 + keyoff + (ks & 3)*32 + l4*8;
      #pragma unroll
      for (int df = 0; df < 2; ++df) {
        long vi = base + (long)(ocol + w*32 + df*16 + l15) * 1024 + kcol;
        bf16x8 vb = *(const bf16x8*)(vt + vi);
        #pragma unroll
        for (int mf = 0; mf < 2; ++mf)
          o[mf][df] = __builtin_amdgcn_mfma_f32_16x16x32_bf16(pa[mf], vb, o[mf][df], 0, 0, 0);
      }
    }
  };

  pv_half(0);
  __syncthreads();

  // ---- stage half B (nf 8..15) ----
  #pragma unroll
  for (int mf = 0; mf < 2; ++mf)
    #pragma unroll
    for (int nf = 8; nf < 16; ++nf)
      #pragma unroll
      for (int r = 0; r < 4; ++r) {
        int ml = mf*16 + l4*4 + r;
        int byte = (ml*1024 + (w*128 + (nf - 8)*16 + l15)*2) ^ ((ml & 7) << 4);
        *(unsigned short*)(smem + byte) = f2bf(s[mf][nf][r]);
      }
  __syncthreads();

  pv_half(128);

  // ---- store outm (bf16, merged [b][m][h*128+d]) ----
  #pragma unroll
  for (int mf = 0; mf < 2; ++mf)
    #pragma unroll
    for (int df = 0; df < 2; ++df)
      #pragma unroll
      for (int r = 0; r < 4; ++r) {
        int row = row0 + mf*16 + l4*4 + r;
        int col = ocol + w*32 + df*16 + l15;
        outm[(long)(bb*1024 + row) * 1024 + col] = f2bf(o[mf][df][r]);
      }
}

// ---------------------------------------------------------------------------
// mask -> bit pack (1 bit per col)
// ---------------------------------------------------------------------------
__global__ __launch_bounds__(256) void pack_mask(const int* __restrict__ mask,
                                                 unsigned int* __restrict__ bits) {
  int w = threadIdx.x >> 6, l = threadIdx.x & 63;
  long rowid = (long)blockIdx.x * 4 + w;
  const int* mrow = mask + rowid * 1024;
  unsigned int* brow = bits + rowid * 32;
  #pragma unroll
  for (int it = 0; it < 16; ++it) {
    unsigned long long b = __ballot(mrow[it*64 + l] != 0);
    if (l == 0) { brow[it*2] = (unsigned int)b; brow[it*2 + 1] = (unsigned int)(b >> 32); }
  }
}

// ---------------------------------------------------------------------------
// LayerNorm over (d_model, seq) per batch: two-stage deterministic reduction.
// ---------------------------------------------------------------------------
__global__ __launch_bounds__(256) void ln_stats1(const float* __restrict__ x, float2* __restrict__ part) {
  __shared__ float2 sred[4];
  int b = blockIdx.y, blk = blockIdx.x;
  const float4* xp = (const float4*)(x + (long)b * 1048576 + (long)blk * 8192);
  float s = 0.f, ss = 0.f;
  for (int i = threadIdx.x; i < 2048; i += 256) {
    float4 v = xp[i];
    s  += v.x + v.y + v.z + v.w;
    ss += v.x*v.x + v.y*v.y + v.z*v.z + v.w*v.w;
  }
  #pragma unroll
  for (int o = 32; o; o >>= 1) { s += __shfl_down(s, o, 64); ss += __shfl_down(ss, o, 64); }
  if ((threadIdx.x & 63) == 0) sred[threadIdx.x >> 6] = make_float2(s, ss);
  __syncthreads();
  if (threadIdx.x == 0) {
    float S = 0.f, SS = 0.f;
    #pragma unroll
    for (int j = 0; j < 4; ++j) { S += sred[j].x; SS += sred[j].y; }
    part[b * 128 + blk] = make_float2(S, SS);
  }
}

__global__ __launch_bounds__(128) void ln_stats2(const float2* __restrict__ part, float2* __restrict__ stats,
                                                 float invN, float eps) {
  __shared__ float2 tmp[2];
  int b = blockIdx.x;
  float2 p = part[b * 128 + threadIdx.x];
  float s = p.x, ss = p.y;
  #pragma unroll
  for (int o = 32; o; o >>= 1) { s += __shfl_down(s, o, 64); ss += __shfl_down(ss, o, 64); }
  if ((threadIdx.x & 63) == 0) tmp[threadIdx.x >> 6] = make_float2(s, ss);
  __syncthreads();
  if (threadIdx.x == 0) {
    float S = tmp[0].x + tmp[1].x, SS = tmp[0].y + tmp[1].y;
    float mu = S * invN;
    float var = SS * invN - mu * mu;
    stats[b] = make_float2(mu, rsqrtf(var + eps));
  }
}

template<bool LO>
__global__ __launch_bounds__(256) void ln_apply(const float* __restrict__ x, const float* __restrict__ g,
                                                const float* __restrict__ be, const float2* __restrict__ stats,
                                                unsigned short* __restrict__ hi, unsigned short* __restrict__ lo) {
  long i = (long)blockIdx.x * 256 + threadIdx.x;
  long e = i << 2;
  int b   = (int)(e >> 20);
  int rem = (int)(e & 1048575);
  float2 st = stats[b];
  float4 xv = ((const float4*)x)[i];
  float4 gv = *(const float4*)(g + rem);
  float4 bv = *(const float4*)(be + rem);
  float h0 = (xv.x - st.x) * st.y * gv.x + bv.x;
  float h1 = (xv.y - st.x) * st.y * gv.y + bv.y;
  float h2 = (xv.z - st.x) * st.y * gv.z + bv.z;
  float h3 = (xv.w - st.x) * st.y * gv.w + bv.w;
  ushort4 h;
  h.x = f2bf(h0); h.y = f2bf(h1); h.z = f2bf(h2); h.w = f2bf(h3);
  ((ushort4*)hi)[i] = h;
  if (LO) {
    ushort4 l4;
    l4.x = f2bf(h0 - bf2f(h.x)); l4.y = f2bf(h1 - bf2f(h.y));
    l4.z = f2bf(h2 - bf2f(h.z)); l4.w = f2bf(h3 - bf2f(h.w));
    ((ushort4*)lo)[i] = l4;
  }
}

__global__ __launch_bounds__(256) void split_bf16(const float* __restrict__ src,
                                                  unsigned short* __restrict__ hi,
                                                  unsigned short* __restrict__ lo) {
  long i = (long)blockIdx.x * 256 + threadIdx.x;
  float4 v = ((const float4*)src)[i];
  ushort4 h, l4;
  h.x = f2bf(v.x); l4.x = f2bf(v.x - bf2f(h.x));
  h.y = f2bf(v.y); l4.y = f2bf(v.y - bf2f(h.y));
  h.z = f2bf(v.z); l4.z = f2bf(v.z - bf2f(h.z));
  h.w = f2bf(v.w); l4.w = f2bf(v.w - bf2f(h.w));
  ((ushort4*)hi)[i] = h;
  ((ushort4*)lo)[i] = l4;
}

__global__ __launch_bounds__(256) void cast_bf16(const float* __restrict__ src,
                                                 unsigned short* __restrict__ dst) {
  long i = (long)blockIdx.x * 256 + threadIdx.x;
  float4 v = ((const float4*)src)[i];
  ushort4 h;
  h.x = f2bf(v.x); h.y = f2bf(v.y); h.z = f2bf(v.z); h.w = f2bf(v.w);
  ((ushort4*)dst)[i] = h;
}

// k-head-norm from split bf16 k (hi+lo reconstruct), write split kn
__global__ __launch_bounds__(256) void knorm_split2(const unsigned short* __restrict__ k1,
                                                    const unsigned short* __restrict__ k2,
                                                    unsigned short* __restrict__ kn1,
                                                    unsigned short* __restrict__ kn2) {
  int t = blockIdx.x * 256 + threadIdx.x;
  int b = t >> 17;
  int rem = t & 131071;
  int m = rem >> 7;
  int d = rem & 127;
  long base = (long)b * 1048576 + (long)m * 1024 + d;
  float v[8]; float s = 0.f;
  #pragma unroll
  for (int h = 0; h < 8; ++h) {
    v[h] = bf2f(k1[base + h * 128]) + bf2f(k2[base + h * 128]);
    s += v[h] * v[h];
  }
  float rn = 1.f / fmaxf(sqrtf(s), 1e-12f);
  #pragma unroll
  for (int h = 0; h < 8; ++h) {
    float f = v[h] * rn;
    unsigned short hv = f2bf(f);
    kn1[base + h * 128] = hv;
    kn2[base + h * 128] = f2bf(f - bf2f(hv));
  }
}

// ---------------------------------------------------------------------------
extern "C" void kernel_launch(void* const* d_in, const int* in_sizes, int n_in,
                              void* d_out, int out_size, void* d_ws, size_t ws_size,
                              hipStream_t stream) {
  const float* enc  = (const float*)d_in[0];
  const int*   mask = (const int*)d_in[1];
  const float* ln1g = (const float*)d_in[2];
  const float* ln1b = (const float*)d_in[3];
  const float* wq   = (const float*)d_in[4];
  const float* wk   = (const float*)d_in[5];
  const float* wv   = (const float*)d_in[6];
  const float* wo   = (const float*)d_in[7];
  const float* ln2g = (const float*)d_in[8];
  const float* ln2b = (const float*)d_in[9];
  const float* w1   = (const float*)d_in[10];
  const float* b1   = (const float*)d_in[11];
  const float* w2   = (const float*)d_in[12];
  const float* b2   = (const float*)d_in[13];

  float* out_enc  = (float*)d_out;
  float* out_attn = out_enc + 8388608;   // [8, 8, 1024, 1024]

  const size_t MB = 1ull << 20;
  char* ws = (char*)d_ws;
  unsigned short* h1   = (unsigned short*)(ws + 0 * MB);     // LN1 hi  [8192,1024]
  unsigned short* h2   = (unsigned short*)(ws + 16 * MB);    // LN1 lo
  unsigned short* q1   = (unsigned short*)(ws + 32 * MB);    // q hi (later h2b)
  unsigned short* q2   = (unsigned short*)(ws + 48 * MB);    // q lo (later tb)
  unsigned short* k1r  = (unsigned short*)(ws + 64 * MB);    // k hi (raw)
  unsigned short* k2r  = (unsigned short*)(ws + 80 * MB);    // k lo (raw)
  unsigned short* kn1  = (unsigned short*)(ws + 96 * MB);    // k-normed hi
  unsigned short* kn2  = (unsigned short*)(ws + 112 * MB);   // k-normed lo
  unsigned short* vt   = (unsigned short*)(ws + 128 * MB);   // v^T per batch [b][o][m]
  unsigned short* outm = (unsigned short*)(ws + 144 * MB);   // attn@v merged [b][m][o]
  float*          x2f  = (float*)(ws + 160 * MB);            // attn-out + residual, f32
  unsigned short* h2b  = (unsigned short*)(ws + 32 * MB);    // LN2 out bf16 (reuse q1)
  unsigned short* tb   = (unsigned short*)(ws + 48 * MB);    // FFN1 out bf16 (reuse q2)
  unsigned short* wq1  = (unsigned short*)(ws + 192 * MB);
  unsigned short* wq2  = (unsigned short*)(ws + 194 * MB);
  unsigned short* wk1  = (unsigned short*)(ws + 196 * MB);
  unsigned short* wk2  = (unsigned short*)(ws + 198 * MB);
  unsigned short* wv1  = (unsigned short*)(ws + 200 * MB);
  unsigned short* wob  = (unsigned short*)(ws + 202 * MB);
  unsigned short* w1b  = (unsigned short*)(ws + 204 * MB);
  unsigned short* w2b  = (unsigned short*)(ws + 206 * MB);
  float2* part  = (float2*)(ws + 208 * MB);
  float2* stats = part + 1024;
  unsigned int* mbits = (unsigned int*)(ws + 209 * MB);      // 1 MB packed mask

  const float invN = 1.f / 1048576.f;

  // ---- LN1 + split ----
  ln_stats1<<<dim3(128, 8), 256, 0, stream>>>(enc, part);
  ln_stats2<<<dim3(8), 128, 0, stream>>>(part, stats, invN, 1e-6f);
  ln_apply<true><<<dim3(8192), 256, 0, stream>>>(enc, ln1g, ln1b, stats, h1, h2);

  // ---- weight casts + mask pack ----
  split_bf16<<<dim3(1024), 256, 0, stream>>>(wq, wq1, wq2);
  split_bf16<<<dim3(1024), 256, 0, stream>>>(wk, wk1, wk2);
  cast_bf16 <<<dim3(1024), 256, 0, stream>>>(wv, wv1);
  cast_bf16 <<<dim3(1024), 256, 0, stream>>>(wo, wob);
  cast_bf16 <<<dim3(1024), 256, 0, stream>>>(w1, w1b);
  cast_bf16 <<<dim3(1024), 256, 0, stream>>>(w2, w2b);
  pack_mask <<<dim3(2048), 256, 0, stream>>>(mask, mbits);

  // ---- q/k projections: fused split pass, split-bf16 output ----
  gemm_split<<<dim3(512), 256, 0, stream>>>(h1, h2, wq1, wq2, q1, q2, 8192, 1024, 1024, 1024, 1024, 1024);
  gemm_split<<<dim3(512), 256, 0, stream>>>(h1, h2, wk1, wk2, k1r, k2r, 8192, 1024, 1024, 1024, 1024, 1024);

  // ---- v projection -> v^T bf16 (per batch) ----
  gemm_bt<2><<<dim3(64, 1, 8), 256, 0, stream>>>(h1, wv1, vt, nullptr, nullptr,
      1024, 1024, 1024, 1024, 1024, 1024, 1, 1048576, 0, 0, 0, 1048576, 0);

  // ---- k head-norm + split ----
  knorm_split2<<<dim3(4096), 256, 0, stream>>>(k1r, k2r, kn1, kn2);

  // ---- fused attention: logits + mask + softmax + attn store + PV ----
  attn_fused<<<dim3(32, 1, 64), 256, 0, stream>>>(q1, q2, kn1, kn2, vt, mbits, out_attn, outm);

  // ---- output projection + residual ----
  gemm_bt<3><<<dim3(512), 256, 0, stream>>>(outm, wob, x2f, nullptr, enc,
      8192, 1024, 1024, 1024, 1024, 1024, 1, 0, 0, 0, 0, 0, 0);

  // ---- LN2 ----
  ln_stats1<<<dim3(128, 8), 256, 0, stream>>>(x2f, part);
  ln_stats2<<<dim3(8), 128, 0, stream>>>(part, stats, invN, 1e-6f);
  ln_apply<false><<<dim3(8192), 256, 0, stream>>>(x2f, ln2g, ln2b, stats, h2b, nullptr);

  // ---- FFN ----
  gemm_bt<4><<<dim3(512), 256, 0, stream>>>(h2b, w1b, tb, b1, nullptr,
      8192, 1024, 1024, 1024, 1024, 1024, 1, 0, 0, 0, 0, 0, 0);
  gemm_bt<5><<<dim3(512), 256, 0, stream>>>(tb, w2b, out_enc, b2, x2f,
      8192, 1024, 1024, 1024, 1024, 1024, 1, 0, 0, 0, 0, 0, 0);
}

// Round 6
// 662.935 us; speedup vs baseline: 1.9271x; 1.9271x over previous
//
#include <hip/hip_runtime.h>

#define DEVINL __device__ __forceinline__

typedef __bf16 bf16x8 __attribute__((ext_vector_type(8)));
typedef float  f32x4  __attribute__((ext_vector_type(4)));

DEVINL unsigned short f2bf(float f) {
  union { float f; unsigned int u; } v; v.f = f;
  unsigned int u = v.u;
  return (unsigned short)((u + 0x7fffu + ((u >> 16) & 1u)) >> 16);
}
DEVINL float bf2f(unsigned short b) {
  union { unsigned int u; float f; } v; v.u = ((unsigned int)b) << 16;
  return v.f;
}

#define GLD_LDS16(SRC, DST) \
  __builtin_amdgcn_global_load_lds((const __attribute__((address_space(1))) void*)(SRC), \
                                   (__attribute__((address_space(3))) void*)(DST), 16, 0, 0)

// ---------------------------------------------------------------------------
// Plain bf16 GEMM: C[M,N] = A[M,K] * B[N,K]^T
// EPI: 2=bf16 transposed store (LDS-transposed, coalesced),
//      3=f32 store + res, 4=bf16 relu(x+bias), 5=f32 x+bias+res
// ---------------------------------------------------------------------------
template<int EPI>
__global__ __launch_bounds__(256) void gemm_bt(
    const unsigned short* __restrict__ Ap, const unsigned short* __restrict__ Bp, void* __restrict__ Cp,
    const float* __restrict__ bias, const float* __restrict__ res,
    int M, int N, int K, int lda, int ldb, int ldc, int H,
    long sAb, long sAh, long sBb, long sBh, long sCb, long sCh)
{
  constexpr int SMEMSZ = (EPI == 2) ? 34816 : 16384;
  __shared__ __align__(16) char smem[SMEMSZ];
  unsigned short* sB = (unsigned short*)(smem + 8192);

  const int tid = threadIdx.x;
  const int w = tid >> 6, l = tid & 63;
  const int wr = w >> 1, wc = w & 1;
  const int ntn = N >> 7;
  const int tm = (int)blockIdx.x / ntn;
  const int tn = (int)blockIdx.x - tm * ntn;
  const int z = blockIdx.z;
  const int bb = z / H, hh = z - bb * H;
  const long offA = (long)bb * sAb + (long)hh * sAh;
  const long offB = (long)bb * sBb + (long)hh * sBh;
  const long offC = (long)bb * sCb + (long)hh * sCh;

  f32x4 zero = {0.f, 0.f, 0.f, 0.f};
  f32x4 acc[4][4];
  #pragma unroll
  for (int m = 0; m < 4; ++m)
    #pragma unroll
    for (int n = 0; n < 4; ++n) acc[m][n] = zero;

  for (int k0 = 0; k0 < K; k0 += 32) {
    __syncthreads();
    const int rl = l >> 2, cl = (l & 3) << 3;
    #pragma unroll
    for (int i = 0; i < 2; ++i) {
      const unsigned short* srcA = Ap + offA + (long)(tm*128 + w*32 + i*16 + rl) * lda + (k0 + cl);
      GLD_LDS16(srcA, (unsigned short*)smem + (w*32 + i*16) * 32);
      const unsigned short* srcB = Bp + offB + (long)(tn*128 + w*32 + i*16 + rl) * ldb + (k0 + cl);
      GLD_LDS16(srcB, sB + (w*32 + i*16) * 32);
    }
    __syncthreads();

    bf16x8 af[4], bfr[4];
    const unsigned short* sA = (const unsigned short*)smem;
    #pragma unroll
    for (int m = 0; m < 4; ++m) {
      int row = wr*64 + m*16 + (l & 15);
      af[m] = *(const bf16x8*)(sA + row*32 + ((l >> 4) << 3));
    }
    #pragma unroll
    for (int n = 0; n < 4; ++n) {
      int row = wc*64 + n*16 + (l & 15);
      bfr[n] = *(const bf16x8*)(sB + row*32 + ((l >> 4) << 3));
    }
    #pragma unroll
    for (int m = 0; m < 4; ++m)
      #pragma unroll
      for (int n = 0; n < 4; ++n)
        acc[m][n] = __builtin_amdgcn_mfma_f32_16x16x32_bf16(af[m], bfr[n], acc[m][n], 0, 0, 0);
  }

  if constexpr (EPI == 2) {
    __syncthreads();
    unsigned short* sT = (unsigned short*)smem;
    #pragma unroll
    for (int m = 0; m < 4; ++m)
      #pragma unroll
      for (int n = 0; n < 4; ++n)
        #pragma unroll
        for (int r = 0; r < 4; ++r) {
          int rowl = wr*64 + m*16 + ((l >> 4) << 2) + r;
          int coll = wc*64 + n*16 + (l & 15);
          sT[coll*136 + rowl] = f2bf(acc[m][n][r]);
        }
    __syncthreads();
    #pragma unroll
    for (int i = 0; i < 8; ++i) {
      int idx = tid + i*256;
      int c = idx >> 4, ch = idx & 15;
      bf16x8 vv = *(const bf16x8*)(sT + c*136 + ch*8);
      *(bf16x8*)((unsigned short*)Cp + offC + (long)(tn*128 + c)*ldc + (tm*128 + ch*8)) = vv;
    }
  } else {
    #pragma unroll
    for (int m = 0; m < 4; ++m) {
      #pragma unroll
      for (int n = 0; n < 4; ++n) {
        #pragma unroll
        for (int r = 0; r < 4; ++r) {
          int row = tm*128 + wr*64 + m*16 + ((l >> 4) << 2) + r;
          int col = tn*128 + wc*64 + n*16 + (l & 15);
          float v = acc[m][n][r];
          long ci = offC + (long)row * ldc + col;
          if constexpr (EPI == 3) {
            ((float*)Cp)[ci] = v + res[ci];
          } else if constexpr (EPI == 4) {
            ((unsigned short*)Cp)[ci] = f2bf(fmaxf(v + bias[col], 0.f));
          } else if constexpr (EPI == 5) {
            ((float*)Cp)[ci] = v + bias[col] + res[ci];
          }
        }
      }
    }
  }
}

// ---------------------------------------------------------------------------
// Fused split-precision GEMM: C = (A1+A2)*(B1+B2)^T (dropping A2*B2),
// split-bf16 output (hi->Cp, lo->Cp2). XCD-grouped tile swizzle: XCD x owns
// tm === x (mod 8), so each A-panel's 8 tn-blocks share one XCD L2.
// ---------------------------------------------------------------------------
__global__ __launch_bounds__(256) void gemm_split(
    const unsigned short* __restrict__ A1, const unsigned short* __restrict__ A2,
    const unsigned short* __restrict__ B1, const unsigned short* __restrict__ B2,
    unsigned short* __restrict__ Cp, unsigned short* __restrict__ Cp2,
    int M, int N, int K, int lda, int ldb, int ldc)
{
  __shared__ __align__(16) unsigned short sAll[4 * 4096];
  unsigned short* sA1 = sAll;
  unsigned short* sA2 = sAll + 4096;
  unsigned short* sB1 = sAll + 8192;
  unsigned short* sB2 = sAll + 12288;

  const int tid = threadIdx.x;
  const int w = tid >> 6, l = tid & 63;
  const int wr = w >> 1, wc = w & 1;
  const int ntn = N >> 7;
  const int ntm = M >> 7;
  int tm, tn;
  if ((ntm & 7) == 0) {          // XCD-grouping swizzle
    const int f = (int)blockIdx.x;
    const int x = f & 7, j = f >> 3;
    const int per = ntm >> 3;
    tm = x + (j % per) * 8;
    tn = j / per;
  } else {
    tm = (int)blockIdx.x / ntn;
    tn = (int)blockIdx.x - tm * ntn;
  }

  f32x4 zero = {0.f, 0.f, 0.f, 0.f};
  f32x4 acc[4][4];
  #pragma unroll
  for (int m = 0; m < 4; ++m)
    #pragma unroll
    for (int n = 0; n < 4; ++n) acc[m][n] = zero;

  const int rl = l >> 2, cl = (l & 3) << 3;

  for (int k0 = 0; k0 < K; k0 += 32) {
    __syncthreads();
    #pragma unroll
    for (int i = 0; i < 2; ++i) {
      const int row = w*32 + i*16;
      const long asrc = (long)(tm*128 + row + rl) * lda + (k0 + cl);
      const long bsrc = (long)(tn*128 + row + rl) * ldb + (k0 + cl);
      GLD_LDS16(A1 + asrc, sA1 + row*32);
      GLD_LDS16(A2 + asrc, sA2 + row*32);
      GLD_LDS16(B1 + bsrc, sB1 + row*32);
      GLD_LDS16(B2 + bsrc, sB2 + row*32);
    }
    __syncthreads();

    bf16x8 a1[4], a2[4], bb4[4];
    int aoff[4], boff[4];
    #pragma unroll
    for (int m = 0; m < 4; ++m) {
      int row = wr*64 + m*16 + (l & 15);
      aoff[m] = row*32 + ((l >> 4) << 3);
      a1[m] = *(const bf16x8*)(sA1 + aoff[m]);
      a2[m] = *(const bf16x8*)(sA2 + aoff[m]);
    }
    #pragma unroll
    for (int n = 0; n < 4; ++n) {
      int row = wc*64 + n*16 + (l & 15);
      boff[n] = row*32 + ((l >> 4) << 3);
      bb4[n] = *(const bf16x8*)(sB1 + boff[n]);
    }
    __builtin_amdgcn_s_setprio(1);
    #pragma unroll
    for (int m = 0; m < 4; ++m)
      #pragma unroll
      for (int n = 0; n < 4; ++n) {
        acc[m][n] = __builtin_amdgcn_mfma_f32_16x16x32_bf16(a1[m], bb4[n], acc[m][n], 0, 0, 0);
        acc[m][n] = __builtin_amdgcn_mfma_f32_16x16x32_bf16(a2[m], bb4[n], acc[m][n], 0, 0, 0);
      }
    __builtin_amdgcn_s_setprio(0);
    #pragma unroll
    for (int n = 0; n < 4; ++n)
      bb4[n] = *(const bf16x8*)(sB2 + boff[n]);
    __builtin_amdgcn_s_setprio(1);
    #pragma unroll
    for (int m = 0; m < 4; ++m)
      #pragma unroll
      for (int n = 0; n < 4; ++n)
        acc[m][n] = __builtin_amdgcn_mfma_f32_16x16x32_bf16(a1[m], bb4[n], acc[m][n], 0, 0, 0);
    __builtin_amdgcn_s_setprio(0);
  }

  #pragma unroll
  for (int m = 0; m < 4; ++m) {
    #pragma unroll
    for (int n = 0; n < 4; ++n) {
      #pragma unroll
      for (int r = 0; r < 4; ++r) {
        int row = tm*128 + wr*64 + m*16 + ((l >> 4) << 2) + r;
        int col = tn*128 + wc*64 + n*16 + (l & 15);
        float v = acc[m][n][r];
        long ci = (long)row * ldc + col;
        unsigned short hv = f2bf(v);
        Cp[ci] = hv;
        Cp2[ci] = f2bf(v - bf2f(hv));
      }
    }
  }
}

// ---------------------------------------------------------------------------
// Fused attention (round-3 structure + XCD z-grouping + setprio):
// flat grid 2048; XCD x owns z in [8x, 8x+8) so kn/vt/q slices of one (b,h)
// are L2-resident on one XCD. Block = (z, 32 q-rows); 4 waves, wave w owns
// key-cols [w*256, +256).
// ---------------------------------------------------------------------------
__global__ __launch_bounds__(256, 2) void attn_fused(
    const unsigned short* __restrict__ q1, const unsigned short* __restrict__ q2,
    const unsigned short* __restrict__ kn1, const unsigned short* __restrict__ kn2,
    const unsigned short* __restrict__ vt, const unsigned int* __restrict__ mbits,
    float* __restrict__ attn, unsigned short* __restrict__ outm)
{
  __shared__ __align__(16) char smem[65536];   // P-LDS (4x16KB) / reductions / PV partials
  const int tid = threadIdx.x;
  const int w = tid >> 6, l = tid & 63;
  const int l15 = l & 15, l4 = l >> 4;

  const int f = (int)blockIdx.x;               // XCD z-grouping swizzle
  const int xcd = f & 7;
  const int j = f >> 3;
  const int z = xcd * 8 + (j >> 5);
  const int row0 = (j & 31) * 32;

  const int bb = z >> 3, hh = z & 7;
  const long base = (long)bb * 1048576;        // [b][m][1024] element stride
  const int ocol = hh * 128;

  f32x4 s[2][16];
  #pragma unroll
  for (int mf = 0; mf < 2; ++mf)
    #pragma unroll
    for (int nf = 0; nf < 16; ++nf) s[mf][nf] = (f32x4){0.f, 0.f, 0.f, 0.f};

  // ---- logits: S = q1*kn1 + q2*kn1 + q1*kn2 ----
  #pragma unroll
  for (int ks = 0; ks < 4; ++ks) {
    const int kk = ocol + ks*32 + l4*8;
    bf16x8 a1[2], a2[2];
    #pragma unroll
    for (int mf = 0; mf < 2; ++mf) {
      long ai = base + (long)(row0 + mf*16 + l15) * 1024 + kk;
      a1[mf] = *(const bf16x8*)(q1 + ai);
      a2[mf] = *(const bf16x8*)(q2 + ai);
    }
    #pragma unroll
    for (int nf = 0; nf < 16; ++nf) {
      long bi = base + (long)(w*256 + nf*16 + l15) * 1024 + kk;
      bf16x8 b1 = *(const bf16x8*)(kn1 + bi);
      bf16x8 b2 = *(const bf16x8*)(kn2 + bi);
      __builtin_amdgcn_s_setprio(1);
      #pragma unroll
      for (int mf = 0; mf < 2; ++mf) {
        s[mf][nf] = __builtin_amdgcn_mfma_f32_16x16x32_bf16(a1[mf], b1, s[mf][nf], 0, 0, 0);
        s[mf][nf] = __builtin_amdgcn_mfma_f32_16x16x32_bf16(a2[mf], b1, s[mf][nf], 0, 0, 0);
        s[mf][nf] = __builtin_amdgcn_mfma_f32_16x16x32_bf16(a1[mf], b2, s[mf][nf], 0, 0, 0);
      }
      __builtin_amdgcn_s_setprio(0);
    }
  }

  // ---- mask (bit-packed: word covers 32 cols) ----
  #pragma unroll
  for (int mf = 0; mf < 2; ++mf) {
    #pragma unroll
    for (int r = 0; r < 4; ++r) {
      int mg = row0 + mf*16 + l4*4 + r;
      const unsigned int* wrow = mbits + (long)bb*32768 + (long)mg*32 + w*8;
      unsigned int wd[8];
      #pragma unroll
      for (int jj = 0; jj < 8; ++jj) wd[jj] = wrow[jj];
      #pragma unroll
      for (int nf = 0; nf < 16; ++nf) {
        unsigned int bit = (wd[nf >> 1] >> (((nf & 1) << 4) + l15)) & 1u;
        if (!bit) s[mf][nf][r] = -1e9f;
      }
    }
  }

  float* red = (float*)smem;   // [4][32], overlaps P region (freed before P writes)

  // ---- row max ----
  float mx[2][4];
  #pragma unroll
  for (int mf = 0; mf < 2; ++mf)
    #pragma unroll
    for (int r = 0; r < 4; ++r) {
      float m = s[mf][0][r];
      #pragma unroll
      for (int nf = 1; nf < 16; ++nf) m = fmaxf(m, s[mf][nf][r]);
      #pragma unroll
      for (int o = 1; o < 16; o <<= 1) m = fmaxf(m, __shfl_xor(m, o, 64));
      mx[mf][r] = m;
      if (l15 == 0) red[w*32 + mf*16 + l4*4 + r] = m;
    }
  __syncthreads();
  #pragma unroll
  for (int mf = 0; mf < 2; ++mf)
    #pragma unroll
    for (int r = 0; r < 4; ++r) {
      int ml = mf*16 + l4*4 + r;
      mx[mf][r] = fmaxf(fmaxf(red[ml], red[32 + ml]), fmaxf(red[64 + ml], red[96 + ml]));
    }
  __syncthreads();

  // ---- exp + row sum ----
  float sm[2][4];
  #pragma unroll
  for (int mf = 0; mf < 2; ++mf)
    #pragma unroll
    for (int r = 0; r < 4; ++r) sm[mf][r] = 0.f;
  #pragma unroll
  for (int mf = 0; mf < 2; ++mf)
    #pragma unroll
    for (int nf = 0; nf < 16; ++nf)
      #pragma unroll
      for (int r = 0; r < 4; ++r) {
        float e = __expf(s[mf][nf][r] - mx[mf][r]);
        s[mf][nf][r] = e;
        sm[mf][r] += e;
      }
  #pragma unroll
  for (int mf = 0; mf < 2; ++mf)
    #pragma unroll
    for (int r = 0; r < 4; ++r) {
      float t = sm[mf][r];
      #pragma unroll
      for (int o = 1; o < 16; o <<= 1) t += __shfl_xor(t, o, 64);
      if (l15 == 0) red[w*32 + mf*16 + l4*4 + r] = t;
    }
  __syncthreads();
  float inv[2][4];
  #pragma unroll
  for (int mf = 0; mf < 2; ++mf)
    #pragma unroll
    for (int r = 0; r < 4; ++r) {
      int ml = mf*16 + l4*4 + r;
      inv[mf][r] = 1.f / (red[ml] + red[32 + ml] + red[64 + ml] + red[96 + ml]);
    }
  __syncthreads();   // red reads done before P overwrites

  // ---- store final attn + write P (bf16, XOR-swizzled) to LDS ----
  char* pbase = smem + w * 16384;
  float* arow = attn + (long)(bb*8 + hh) * 1048576;
  #pragma unroll
  for (int mf = 0; mf < 2; ++mf)
    #pragma unroll
    for (int nf = 0; nf < 16; ++nf)
      #pragma unroll
      for (int r = 0; r < 4; ++r) {
        int ml = mf*16 + l4*4 + r;
        int cl = nf*16 + l15;
        float a = s[mf][nf][r] * inv[mf][r];
        arow[(long)(row0 + ml) * 1024 + (w*256 + cl)] = a;
        int byte = (ml*512 + cl*2) ^ ((ml & 7) << 4);
        *(unsigned short*)(pbase + byte) = f2bf(a);
      }
  __syncthreads();

  // ---- PV: wave-partial over its 256 keys ----
  f32x4 o[2][8];
  #pragma unroll
  for (int mf = 0; mf < 2; ++mf)
    #pragma unroll
    for (int df = 0; df < 8; ++df) o[mf][df] = (f32x4){0.f, 0.f, 0.f, 0.f};
  #pragma unroll
  for (int ks = 0; ks < 8; ++ks) {
    bf16x8 pa[2];
    #pragma unroll
    for (int mf = 0; mf < 2; ++mf) {
      int ml = mf*16 + l15;
      int byte = (ml*512 + (ks*32 + l4*8)*2) ^ ((ml & 7) << 4);
      pa[mf] = *(const bf16x8*)(pbase + byte);
    }
    #pragma unroll
    for (int df = 0; df < 8; ++df) {
      long vi = base + (long)(ocol + df*16 + l15) * 1024 + (w*256 + ks*32 + l4*8);
      bf16x8 vb = *(const bf16x8*)(vt + vi);
      __builtin_amdgcn_s_setprio(1);
      #pragma unroll
      for (int mf = 0; mf < 2; ++mf)
        o[mf][df] = __builtin_amdgcn_mfma_f32_16x16x32_bf16(pa[mf], vb, o[mf][df], 0, 0, 0);
      __builtin_amdgcn_s_setprio(0);
    }
  }
  __syncthreads();

  // ---- cross-wave reduce of PV partials ----
  float* pp = (float*)smem + w * 4096;   // [32][128] per wave
  #pragma unroll
  for (int mf = 0; mf < 2; ++mf)
    #pragma unroll
    for (int df = 0; df < 8; ++df)
      #pragma unroll
      for (int r = 0; r < 4; ++r)
        pp[(mf*16 + l4*4 + r)*128 + df*16 + l15] = o[mf][df][r];
  __syncthreads();
  #pragma unroll
  for (int it = 0; it < 4; ++it) {
    int i = tid + it*256;
    f32x4 a4 = ((const f32x4*)smem)[i];
    a4 += ((const f32x4*)(smem + 16384))[i];
    a4 += ((const f32x4*)(smem + 32768))[i];
    a4 += ((const f32x4*)(smem + 49152))[i];
    int ml = i >> 5, d0 = (i & 31) << 2;
    ushort4 st;
    st.x = f2bf(a4[0]); st.y = f2bf(a4[1]); st.z = f2bf(a4[2]); st.w = f2bf(a4[3]);
    *(ushort4*)(outm + (long)(bb*1024 + row0 + ml) * 1024 + ocol + d0) = st;
  }
}

// ---------------------------------------------------------------------------
// mask -> bit pack (1 bit per col)
// ---------------------------------------------------------------------------
__global__ __launch_bounds__(256) void pack_mask(const int* __restrict__ mask,
                                                 unsigned int* __restrict__ bits) {
  int w = threadIdx.x >> 6, l = threadIdx.x & 63;
  long rowid = (long)blockIdx.x * 4 + w;
  const int* mrow = mask + rowid * 1024;
  unsigned int* brow = bits + rowid * 32;
  #pragma unroll
  for (int it = 0; it < 16; ++it) {
    unsigned long long b = __ballot(mrow[it*64 + l] != 0);
    if (l == 0) { brow[it*2] = (unsigned int)b; brow[it*2 + 1] = (unsigned int)(b >> 32); }
  }
}

// ---------------------------------------------------------------------------
// LayerNorm over (d_model, seq) per batch: two-stage deterministic reduction.
// ---------------------------------------------------------------------------
__global__ __launch_bounds__(256) void ln_stats1(const float* __restrict__ x, float2* __restrict__ part) {
  __shared__ float2 sred[4];
  int b = blockIdx.y, blk = blockIdx.x;
  const float4* xp = (const float4*)(x + (long)b * 1048576 + (long)blk * 8192);
  float s = 0.f, ss = 0.f;
  for (int i = threadIdx.x; i < 2048; i += 256) {
    float4 v = xp[i];
    s  += v.x + v.y + v.z + v.w;
    ss += v.x*v.x + v.y*v.y + v.z*v.z + v.w*v.w;
  }
  #pragma unroll
  for (int o = 32; o; o >>= 1) { s += __shfl_down(s, o, 64); ss += __shfl_down(ss, o, 64); }
  if ((threadIdx.x & 63) == 0) sred[threadIdx.x >> 6] = make_float2(s, ss);
  __syncthreads();
  if (threadIdx.x == 0) {
    float S = 0.f, SS = 0.f;
    #pragma unroll
    for (int j = 0; j < 4; ++j) { S += sred[j].x; SS += sred[j].y; }
    part[b * 128 + blk] = make_float2(S, SS);
  }
}

__global__ __launch_bounds__(128) void ln_stats2(const float2* __restrict__ part, float2* __restrict__ stats,
                                                 float invN, float eps) {
  __shared__ float2 tmp[2];
  int b = blockIdx.x;
  float2 p = part[b * 128 + threadIdx.x];
  float s = p.x, ss = p.y;
  #pragma unroll
  for (int o = 32; o; o >>= 1) { s += __shfl_down(s, o, 64); ss += __shfl_down(ss, o, 64); }
  if ((threadIdx.x & 63) == 0) tmp[threadIdx.x >> 6] = make_float2(s, ss);
  __syncthreads();
  if (threadIdx.x == 0) {
    float S = tmp[0].x + tmp[1].x, SS = tmp[0].y + tmp[1].y;
    float mu = S * invN;
    float var = SS * invN - mu * mu;
    stats[b] = make_float2(mu, rsqrtf(var + eps));
  }
}

template<bool LO>
__global__ __launch_bounds__(256) void ln_apply(const float* __restrict__ x, const float* __restrict__ g,
                                                const float* __restrict__ be, const float2* __restrict__ stats,
                                                unsigned short* __restrict__ hi, unsigned short* __restrict__ lo) {
  long i = (long)blockIdx.x * 256 + threadIdx.x;
  long e = i << 2;
  int b   = (int)(e >> 20);
  int rem = (int)(e & 1048575);
  float2 st = stats[b];
  float4 xv = ((const float4*)x)[i];
  float4 gv = *(const float4*)(g + rem);
  float4 bv = *(const float4*)(be + rem);
  float h0 = (xv.x - st.x) * st.y * gv.x + bv.x;
  float h1 = (xv.y - st.x) * st.y * gv.y + bv.y;
  float h2 = (xv.z - st.x) * st.y * gv.z + bv.z;
  float h3 = (xv.w - st.x) * st.y * gv.w + bv.w;
  ushort4 h;
  h.x = f2bf(h0); h.y = f2bf(h1); h.z = f2bf(h2); h.w = f2bf(h3);
  ((ushort4*)hi)[i] = h;
  if (LO) {
    ushort4 l4;
    l4.x = f2bf(h0 - bf2f(h.x)); l4.y = f2bf(h1 - bf2f(h.y));
    l4.z = f2bf(h2 - bf2f(h.z)); l4.w = f2bf(h3 - bf2f(h.w));
    ((ushort4*)lo)[i] = l4;
  }
}

__global__ __launch_bounds__(256) void split_bf16(const float* __restrict__ src,
                                                  unsigned short* __restrict__ hi,
                                                  unsigned short* __restrict__ lo) {
  long i = (long)blockIdx.x * 256 + threadIdx.x;
  float4 v = ((const float4*)src)[i];
  ushort4 h, l4;
  h.x = f2bf(v.x); l4.x = f2bf(v.x - bf2f(h.x));
  h.y = f2bf(v.y); l4.y = f2bf(v.y - bf2f(h.y));
  h.z = f2bf(v.z); l4.z = f2bf(v.z - bf2f(h.z));
  h.w = f2bf(v.w); l4.w = f2bf(v.w - bf2f(h.w));
  ((ushort4*)hi)[i] = h;
  ((ushort4*)lo)[i] = l4;
}

__global__ __launch_bounds__(256) void cast_bf16(const float* __restrict__ src,
                                                 unsigned short* __restrict__ dst) {
  long i = (long)blockIdx.x * 256 + threadIdx.x;
  float4 v = ((const float4*)src)[i];
  ushort4 h;
  h.x = f2bf(v.x); h.y = f2bf(v.y); h.z = f2bf(v.z); h.w = f2bf(v.w);
  ((ushort4*)dst)[i] = h;
}

// k-head-norm from split bf16 k (hi+lo reconstruct), write split kn
__global__ __launch_bounds__(256) void knorm_split2(const unsigned short* __restrict__ k1,
                                                    const unsigned short* __restrict__ k2,
                                                    unsigned short* __restrict__ kn1,
                                                    unsigned short* __restrict__ kn2) {
  int t = blockIdx.x * 256 + threadIdx.x;
  int b = t >> 17;
  int rem = t & 131071;
  int m = rem >> 7;
  int d = rem & 127;
  long base = (long)b * 1048576 + (long)m * 1024 + d;
  float v[8]; float s = 0.f;
  #pragma unroll
  for (int h = 0; h < 8; ++h) {
    v[h] = bf2f(k1[base + h * 128]) + bf2f(k2[base + h * 128]);
    s += v[h] * v[h];
  }
  float rn = 1.f / fmaxf(sqrtf(s), 1e-12f);
  #pragma unroll
  for (int h = 0; h < 8; ++h) {
    float f = v[h] * rn;
    unsigned short hv = f2bf(f);
    kn1[base + h * 128] = hv;
    kn2[base + h * 128] = f2bf(f - bf2f(hv));
  }
}

// ---------------------------------------------------------------------------
extern "C" void kernel_launch(void* const* d_in, const int* in_sizes, int n_in,
                              void* d_out, int out_size, void* d_ws, size_t ws_size,
                              hipStream_t stream) {
  const float* enc  = (const float*)d_in[0];
  const int*   mask = (const int*)d_in[1];
  const float* ln1g = (const float*)d_in[2];
  const float* ln1b = (const float*)d_in[3];
  const float* wq   = (const float*)d_in[4];
  const float* wk   = (const float*)d_in[5];
  const float* wv   = (const float*)d_in[6];
  const float* wo   = (const float*)d_in[7];
  const float* ln2g = (const float*)d_in[8];
  const float* ln2b = (const float*)d_in[9];
  const float* w1   = (const float*)d_in[10];
  const float* b1   = (const float*)d_in[11];
  const float* w2   = (const float*)d_in[12];
  const float* b2   = (const float*)d_in[13];

  float* out_enc  = (float*)d_out;
  float* out_attn = out_enc + 8388608;   // [8, 8, 1024, 1024]

  const size_t MB = 1ull << 20;
  char* ws = (char*)d_ws;
  unsigned short* h1   = (unsigned short*)(ws + 0 * MB);     // LN1 hi  [8192,1024]
  unsigned short* h2   = (unsigned short*)(ws + 16 * MB);    // LN1 lo
  unsigned short* q1   = (unsigned short*)(ws + 32 * MB);    // q hi (later h2b)
  unsigned short* q2   = (unsigned short*)(ws + 48 * MB);    // q lo (later tb)
  unsigned short* k1r  = (unsigned short*)(ws + 64 * MB);    // k hi (raw)
  unsigned short* k2r  = (unsigned short*)(ws + 80 * MB);    // k lo (raw)
  unsigned short* kn1  = (unsigned short*)(ws + 96 * MB);    // k-normed hi
  unsigned short* kn2  = (unsigned short*)(ws + 112 * MB);   // k-normed lo
  unsigned short* vt   = (unsigned short*)(ws + 128 * MB);   // v^T per batch [b][o][m]
  unsigned short* outm = (unsigned short*)(ws + 144 * MB);   // attn@v merged [b][m][o]
  float*          x2f  = (float*)(ws + 160 * MB);            // attn-out + residual, f32
  unsigned short* h2b  = (unsigned short*)(ws + 32 * MB);    // LN2 out bf16 (reuse q1)
  unsigned short* tb   = (unsigned short*)(ws + 48 * MB);    // FFN1 out bf16 (reuse q2)
  unsigned short* wq1  = (unsigned short*)(ws + 192 * MB);
  unsigned short* wq2  = (unsigned short*)(ws + 194 * MB);
  unsigned short* wk1  = (unsigned short*)(ws + 196 * MB);
  unsigned short* wk2  = (unsigned short*)(ws + 198 * MB);
  unsigned short* wv1  = (unsigned short*)(ws + 200 * MB);
  unsigned short* wob  = (unsigned short*)(ws + 202 * MB);
  unsigned short* w1b  = (unsigned short*)(ws + 204 * MB);
  unsigned short* w2b  = (unsigned short*)(ws + 206 * MB);
  float2* part  = (float2*)(ws + 208 * MB);
  float2* stats = part + 1024;
  unsigned int* mbits = (unsigned int*)(ws + 209 * MB);      // 1 MB packed mask

  const float invN = 1.f / 1048576.f;

  // ---- LN1 + split ----
  ln_stats1<<<dim3(128, 8), 256, 0, stream>>>(enc, part);
  ln_stats2<<<dim3(8), 128, 0, stream>>>(part, stats, invN, 1e-6f);
  ln_apply<true><<<dim3(8192), 256, 0, stream>>>(enc, ln1g, ln1b, stats, h1, h2);

  // ---- weight casts + mask pack ----
  split_bf16<<<dim3(1024), 256, 0, stream>>>(wq, wq1, wq2);
  split_bf16<<<dim3(1024), 256, 0, stream>>>(wk, wk1, wk2);
  cast_bf16 <<<dim3(1024), 256, 0, stream>>>(wv, wv1);
  cast_bf16 <<<dim3(1024), 256, 0, stream>>>(wo, wob);
  cast_bf16 <<<dim3(1024), 256, 0, stream>>>(w1, w1b);
  cast_bf16 <<<dim3(1024), 256, 0, stream>>>(w2, w2b);
  pack_mask <<<dim3(2048), 256, 0, stream>>>(mask, mbits);

  // ---- q/k projections: fused split pass, split-bf16 output ----
  gemm_split<<<dim3(512), 256, 0, stream>>>(h1, h2, wq1, wq2, q1, q2, 8192, 1024, 1024, 1024, 1024, 1024);
  gemm_split<<<dim3(512), 256, 0, stream>>>(h1, h2, wk1, wk2, k1r, k2r, 8192, 1024, 1024, 1024, 1024, 1024);

  // ---- v projection -> v^T bf16 (per batch) ----
  gemm_bt<2><<<dim3(64, 1, 8), 256, 0, stream>>>(h1, wv1, vt, nullptr, nullptr,
      1024, 1024, 1024, 1024, 1024, 1024, 1, 1048576, 0, 0, 0, 1048576, 0);

  // ---- k head-norm + split ----
  knorm_split2<<<dim3(4096), 256, 0, stream>>>(k1r, k2r, kn1, kn2);

  // ---- fused attention: logits + mask + softmax + attn store + PV ----
  attn_fused<<<dim3(2048), 256, 0, stream>>>(q1, q2, kn1, kn2, vt, mbits, out_attn, outm);

  // ---- output projection + residual ----
  gemm_bt<3><<<dim3(512), 256, 0, stream>>>(outm, wob, x2f, nullptr, enc,
      8192, 1024, 1024, 1024, 1024, 1024, 1, 0, 0, 0, 0, 0, 0);

  // ---- LN2 ----
  ln_stats1<<<dim3(128, 8), 256, 0, stream>>>(x2f, part);
  ln_stats2<<<dim3(8), 128, 0, stream>>>(part, stats, invN, 1e-6f);
  ln_apply<false><<<dim3(8192), 256, 0, stream>>>(x2f, ln2g, ln2b, stats, h2b, nullptr);

  // ---- FFN ----
  gemm_bt<4><<<dim3(512), 256, 0, stream>>>(h2b, w1b, tb, b1, nullptr,
      8192, 1024, 1024, 1024, 1024, 1024, 1, 0, 0, 0, 0, 0, 0);
  gemm_bt<5><<<dim3(512), 256, 0, stream>>>(tb, w2b, out_enc, b2, x2f,
      8192, 1024, 1024, 1024, 1024, 1024, 1, 0, 0, 0, 0, 0, 0);
}

// Round 8
// 607.374 us; speedup vs baseline: 2.1034x; 1.0915x over previous
//
#include <hip/hip_runtime.h>

#define DEVINL __device__ __forceinline__

typedef __bf16 bf16x8 __attribute__((ext_vector_type(8)));
typedef float  f32x4  __attribute__((ext_vector_type(4)));

DEVINL unsigned short f2bf(float f) {
  union { float f; unsigned int u; } v; v.f = f;
  unsigned int u = v.u;
  return (unsigned short)((u + 0x7fffu + ((u >> 16) & 1u)) >> 16);
}
DEVINL float bf2f(unsigned short b) {
  union { unsigned int u; float f; } v; v.u = ((unsigned int)b) << 16;
  return v.f;
}

#define GLD_LDS16(SRC, DST) \
  __builtin_amdgcn_global_load_lds((const __attribute__((address_space(1))) void*)(SRC), \
                                   (__attribute__((address_space(3))) void*)(DST), 16, 0, 0)

// ---------------------------------------------------------------------------
// Plain bf16 GEMM: C[M,N] = A[M,K] * B[N,K]^T
// EPI: 2=bf16 transposed store (LDS-transposed, coalesced),
//      3=f32 store + res, 4=bf16 relu(x+bias), 5=f32 x+bias+res
// ---------------------------------------------------------------------------
template<int EPI>
__global__ __launch_bounds__(256) void gemm_bt(
    const unsigned short* __restrict__ Ap, const unsigned short* __restrict__ Bp, void* __restrict__ Cp,
    const float* __restrict__ bias, const float* __restrict__ res,
    int M, int N, int K, int lda, int ldb, int ldc, int H,
    long sAb, long sAh, long sBb, long sBh, long sCb, long sCh)
{
  constexpr int SMEMSZ = (EPI == 2) ? 34816 : 16384;
  __shared__ __align__(16) char smem[SMEMSZ];
  unsigned short* sB = (unsigned short*)(smem + 8192);

  const int tid = threadIdx.x;
  const int w = tid >> 6, l = tid & 63;
  const int wr = w >> 1, wc = w & 1;
  const int ntn = N >> 7;
  const int tm = (int)blockIdx.x / ntn;
  const int tn = (int)blockIdx.x - tm * ntn;
  const int z = blockIdx.z;
  const int bb = z / H, hh = z - bb * H;
  const long offA = (long)bb * sAb + (long)hh * sAh;
  const long offB = (long)bb * sBb + (long)hh * sBh;
  const long offC = (long)bb * sCb + (long)hh * sCh;

  f32x4 zero = {0.f, 0.f, 0.f, 0.f};
  f32x4 acc[4][4];
  #pragma unroll
  for (int m = 0; m < 4; ++m)
    #pragma unroll
    for (int n = 0; n < 4; ++n) acc[m][n] = zero;

  for (int k0 = 0; k0 < K; k0 += 32) {
    __syncthreads();
    const int rl = l >> 2, cl = (l & 3) << 3;
    #pragma unroll
    for (int i = 0; i < 2; ++i) {
      const unsigned short* srcA = Ap + offA + (long)(tm*128 + w*32 + i*16 + rl) * lda + (k0 + cl);
      GLD_LDS16(srcA, (unsigned short*)smem + (w*32 + i*16) * 32);
      const unsigned short* srcB = Bp + offB + (long)(tn*128 + w*32 + i*16 + rl) * ldb + (k0 + cl);
      GLD_LDS16(srcB, sB + (w*32 + i*16) * 32);
    }
    __syncthreads();

    bf16x8 af[4], bfr[4];
    const unsigned short* sA = (const unsigned short*)smem;
    #pragma unroll
    for (int m = 0; m < 4; ++m) {
      int row = wr*64 + m*16 + (l & 15);
      af[m] = *(const bf16x8*)(sA + row*32 + ((l >> 4) << 3));
    }
    #pragma unroll
    for (int n = 0; n < 4; ++n) {
      int row = wc*64 + n*16 + (l & 15);
      bfr[n] = *(const bf16x8*)(sB + row*32 + ((l >> 4) << 3));
    }
    #pragma unroll
    for (int m = 0; m < 4; ++m)
      #pragma unroll
      for (int n = 0; n < 4; ++n)
        acc[m][n] = __builtin_amdgcn_mfma_f32_16x16x32_bf16(af[m], bfr[n], acc[m][n], 0, 0, 0);
  }

  if constexpr (EPI == 2) {
    __syncthreads();
    unsigned short* sT = (unsigned short*)smem;
    #pragma unroll
    for (int m = 0; m < 4; ++m)
      #pragma unroll
      for (int n = 0; n < 4; ++n)
        #pragma unroll
        for (int r = 0; r < 4; ++r) {
          int rowl = wr*64 + m*16 + ((l >> 4) << 2) + r;
          int coll = wc*64 + n*16 + (l & 15);
          sT[coll*136 + rowl] = f2bf(acc[m][n][r]);
        }
    __syncthreads();
    #pragma unroll
    for (int i = 0; i < 8; ++i) {
      int idx = tid + i*256;
      int c = idx >> 4, ch = idx & 15;
      bf16x8 vv = *(const bf16x8*)(sT + c*136 + ch*8);
      *(bf16x8*)((unsigned short*)Cp + offC + (long)(tn*128 + c)*ldc + (tm*128 + ch*8)) = vv;
    }
  } else {
    #pragma unroll
    for (int m = 0; m < 4; ++m) {
      #pragma unroll
      for (int n = 0; n < 4; ++n) {
        #pragma unroll
        for (int r = 0; r < 4; ++r) {
          int row = tm*128 + wr*64 + m*16 + ((l >> 4) << 2) + r;
          int col = tn*128 + wc*64 + n*16 + (l & 15);
          float v = acc[m][n][r];
          long ci = offC + (long)row * ldc + col;
          if constexpr (EPI == 3) {
            ((float*)Cp)[ci] = v + res[ci];
          } else if constexpr (EPI == 4) {
            ((unsigned short*)Cp)[ci] = f2bf(fmaxf(v + bias[col], 0.f));
          } else if constexpr (EPI == 5) {
            ((float*)Cp)[ci] = v + bias[col] + res[ci];
          }
        }
      }
    }
  }
}

// ---------------------------------------------------------------------------
// Fused split-precision GEMM: C = (A1+A2)*(B1+B2)^T (dropping A2*B2),
// split-bf16 output (hi->Cp, lo->Cp2).  (r3-proven form)
// ---------------------------------------------------------------------------
__global__ __launch_bounds__(256) void gemm_split(
    const unsigned short* __restrict__ A1, const unsigned short* __restrict__ A2,
    const unsigned short* __restrict__ B1, const unsigned short* __restrict__ B2,
    unsigned short* __restrict__ Cp, unsigned short* __restrict__ Cp2,
    int M, int N, int K, int lda, int ldb, int ldc)
{
  __shared__ __align__(16) unsigned short sAll[4 * 4096];
  unsigned short* sA1 = sAll;
  unsigned short* sA2 = sAll + 4096;
  unsigned short* sB1 = sAll + 8192;
  unsigned short* sB2 = sAll + 12288;

  const int tid = threadIdx.x;
  const int w = tid >> 6, l = tid & 63;
  const int wr = w >> 1, wc = w & 1;
  const int ntn = N >> 7;
  const int tm = (int)blockIdx.x / ntn;
  const int tn = (int)blockIdx.x - tm * ntn;

  f32x4 zero = {0.f, 0.f, 0.f, 0.f};
  f32x4 acc[4][4];
  #pragma unroll
  for (int m = 0; m < 4; ++m)
    #pragma unroll
    for (int n = 0; n < 4; ++n) acc[m][n] = zero;

  const int rl = l >> 2, cl = (l & 3) << 3;

  for (int k0 = 0; k0 < K; k0 += 32) {
    __syncthreads();
    #pragma unroll
    for (int i = 0; i < 2; ++i) {
      const int row = w*32 + i*16;
      const long asrc = (long)(tm*128 + row + rl) * lda + (k0 + cl);
      const long bsrc = (long)(tn*128 + row + rl) * ldb + (k0 + cl);
      GLD_LDS16(A1 + asrc, sA1 + row*32);
      GLD_LDS16(A2 + asrc, sA2 + row*32);
      GLD_LDS16(B1 + bsrc, sB1 + row*32);
      GLD_LDS16(B2 + bsrc, sB2 + row*32);
    }
    __syncthreads();

    bf16x8 a1[4], a2[4], bb4[4];
    int aoff[4], boff[4];
    #pragma unroll
    for (int m = 0; m < 4; ++m) {
      int row = wr*64 + m*16 + (l & 15);
      aoff[m] = row*32 + ((l >> 4) << 3);
      a1[m] = *(const bf16x8*)(sA1 + aoff[m]);
      a2[m] = *(const bf16x8*)(sA2 + aoff[m]);
    }
    #pragma unroll
    for (int n = 0; n < 4; ++n) {
      int row = wc*64 + n*16 + (l & 15);
      boff[n] = row*32 + ((l >> 4) << 3);
      bb4[n] = *(const bf16x8*)(sB1 + boff[n]);
    }
    #pragma unroll
    for (int m = 0; m < 4; ++m)
      #pragma unroll
      for (int n = 0; n < 4; ++n) {
        acc[m][n] = __builtin_amdgcn_mfma_f32_16x16x32_bf16(a1[m], bb4[n], acc[m][n], 0, 0, 0);
        acc[m][n] = __builtin_amdgcn_mfma_f32_16x16x32_bf16(a2[m], bb4[n], acc[m][n], 0, 0, 0);
      }
    #pragma unroll
    for (int n = 0; n < 4; ++n)
      bb4[n] = *(const bf16x8*)(sB2 + boff[n]);
    #pragma unroll
    for (int m = 0; m < 4; ++m)
      #pragma unroll
      for (int n = 0; n < 4; ++n)
        acc[m][n] = __builtin_amdgcn_mfma_f32_16x16x32_bf16(a1[m], bb4[n], acc[m][n], 0, 0, 0);
  }

  #pragma unroll
  for (int m = 0; m < 4; ++m) {
    #pragma unroll
    for (int n = 0; n < 4; ++n) {
      #pragma unroll
      for (int r = 0; r < 4; ++r) {
        int row = tm*128 + wr*64 + m*16 + ((l >> 4) << 2) + r;
        int col = tn*128 + wc*64 + n*16 + (l & 15);
        float v = acc[m][n][r];
        long ci = (long)row * ldc + col;
        unsigned short hv = f2bf(v);
        Cp[ci] = hv;
        Cp2[ci] = f2bf(v - bf2f(hv));
      }
    }
  }
}

// ---------------------------------------------------------------------------
// Fused attention v5 = r3 structure + XCD z-grouping + batched register
// operand loads (ILP; numerically bit-identical to r3).
// Flat grid 2048; XCD x owns z in [8x, 8x+8). Block = (z, 32 q-rows);
// 4 waves, wave w owns key-cols [w*256, +256).
// ---------------------------------------------------------------------------
__global__ __launch_bounds__(256, 2) void attn_fused(
    const unsigned short* __restrict__ q1, const unsigned short* __restrict__ q2,
    const unsigned short* __restrict__ kn1, const unsigned short* __restrict__ kn2,
    const unsigned short* __restrict__ vt, const unsigned int* __restrict__ mbits,
    float* __restrict__ attn, unsigned short* __restrict__ outm)
{
  __shared__ __align__(16) char smem[65536];   // P-LDS (4x16KB) / reductions / PV partials
  const int tid = threadIdx.x;
  const int w = tid >> 6, l = tid & 63;
  const int l15 = l & 15, l4 = l >> 4;

  const int f = (int)blockIdx.x;               // XCD z-grouping swizzle
  const int xcd = f & 7;
  const int j = f >> 3;
  const int z = xcd * 8 + (j >> 5);
  const int row0 = (j & 31) * 32;

  const int bb = z >> 3, hh = z & 7;
  const long base = (long)bb * 1048576;        // [b][m][1024] element stride
  const int ocol = hh * 128;

  // ---- q fragments hoisted (reused across all nf) ----
  bf16x8 a1[2][4], a2[2][4];
  #pragma unroll
  for (int ks = 0; ks < 4; ++ks)
    #pragma unroll
    for (int mf = 0; mf < 2; ++mf) {
      long ai = base + (long)(row0 + mf*16 + l15) * 1024 + (ocol + ks*32 + l4*8);
      a1[mf][ks] = *(const bf16x8*)(q1 + ai);
      a2[mf][ks] = *(const bf16x8*)(q2 + ai);
    }

  f32x4 s[2][16];
  #pragma unroll
  for (int mf = 0; mf < 2; ++mf)
    #pragma unroll
    for (int nf = 0; nf < 16; ++nf) s[mf][nf] = (f32x4){0.f, 0.f, 0.f, 0.f};

  // ---- logits: S = q1*kn1 + q2*kn1 + q1*kn2 ; batched b-loads (MLP=8) ----
  #pragma unroll
  for (int nf = 0; nf < 16; ++nf) {
    bf16x8 b1[4], b2[4];
    #pragma unroll
    for (int ks = 0; ks < 4; ++ks) {
      long bi = base + (long)(w*256 + nf*16 + l15) * 1024 + (ocol + ks*32 + l4*8);
      b1[ks] = *(const bf16x8*)(kn1 + bi);
      b2[ks] = *(const bf16x8*)(kn2 + bi);
    }
    #pragma unroll
    for (int ks = 0; ks < 4; ++ks)
      #pragma unroll
      for (int mf = 0; mf < 2; ++mf) {
        s[mf][nf] = __builtin_amdgcn_mfma_f32_16x16x32_bf16(a1[mf][ks], b1[ks], s[mf][nf], 0, 0, 0);
        s[mf][nf] = __builtin_amdgcn_mfma_f32_16x16x32_bf16(a2[mf][ks], b1[ks], s[mf][nf], 0, 0, 0);
        s[mf][nf] = __builtin_amdgcn_mfma_f32_16x16x32_bf16(a1[mf][ks], b2[ks], s[mf][nf], 0, 0, 0);
      }
  }

  // ---- mask (bit-packed: word covers 32 cols) ----
  #pragma unroll
  for (int mf = 0; mf < 2; ++mf) {
    #pragma unroll
    for (int r = 0; r < 4; ++r) {
      int mg = row0 + mf*16 + l4*4 + r;
      const unsigned int* wrow = mbits + (long)bb*32768 + (long)mg*32 + w*8;
      unsigned int wd[8];
      #pragma unroll
      for (int jj = 0; jj < 8; ++jj) wd[jj] = wrow[jj];
      #pragma unroll
      for (int nf = 0; nf < 16; ++nf) {
        unsigned int bit = (wd[nf >> 1] >> (((nf & 1) << 4) + l15)) & 1u;
        if (!bit) s[mf][nf][r] = -1e9f;
      }
    }
  }

  float* red = (float*)smem;   // [4][32], overlaps P region (freed before P writes)

  // ---- row max ----
  float mx[2][4];
  #pragma unroll
  for (int mf = 0; mf < 2; ++mf)
    #pragma unroll
    for (int r = 0; r < 4; ++r) {
      float m = s[mf][0][r];
      #pragma unroll
      for (int nf = 1; nf < 16; ++nf) m = fmaxf(m, s[mf][nf][r]);
      #pragma unroll
      for (int o = 1; o < 16; o <<= 1) m = fmaxf(m, __shfl_xor(m, o, 64));
      mx[mf][r] = m;
      if (l15 == 0) red[w*32 + mf*16 + l4*4 + r] = m;
    }
  __syncthreads();
  #pragma unroll
  for (int mf = 0; mf < 2; ++mf)
    #pragma unroll
    for (int r = 0; r < 4; ++r) {
      int ml = mf*16 + l4*4 + r;
      mx[mf][r] = fmaxf(fmaxf(red[ml], red[32 + ml]), fmaxf(red[64 + ml], red[96 + ml]));
    }
  __syncthreads();

  // ---- exp + row sum ----
  float sm[2][4];
  #pragma unroll
  for (int mf = 0; mf < 2; ++mf)
    #pragma unroll
    for (int r = 0; r < 4; ++r) sm[mf][r] = 0.f;
  #pragma unroll
  for (int mf = 0; mf < 2; ++mf)
    #pragma unroll
    for (int nf = 0; nf < 16; ++nf)
      #pragma unroll
      for (int r = 0; r < 4; ++r) {
        float e = __expf(s[mf][nf][r] - mx[mf][r]);
        s[mf][nf][r] = e;
        sm[mf][r] += e;
      }
  #pragma unroll
  for (int mf = 0; mf < 2; ++mf)
    #pragma unroll
    for (int r = 0; r < 4; ++r) {
      float t = sm[mf][r];
      #pragma unroll
      for (int o = 1; o < 16; o <<= 1) t += __shfl_xor(t, o, 64);
      if (l15 == 0) red[w*32 + mf*16 + l4*4 + r] = t;
    }
  __syncthreads();
  float inv[2][4];
  #pragma unroll
  for (int mf = 0; mf < 2; ++mf)
    #pragma unroll
    for (int r = 0; r < 4; ++r) {
      int ml = mf*16 + l4*4 + r;
      inv[mf][r] = 1.f / (red[ml] + red[32 + ml] + red[64 + ml] + red[96 + ml]);
    }
  __syncthreads();   // red reads done before P overwrites

  // ---- store final attn + write P (bf16, XOR-swizzled) to LDS ----
  char* pbase = smem + w * 16384;
  float* arow = attn + (long)(bb*8 + hh) * 1048576;
  #pragma unroll
  for (int mf = 0; mf < 2; ++mf)
    #pragma unroll
    for (int nf = 0; nf < 16; ++nf)
      #pragma unroll
      for (int r = 0; r < 4; ++r) {
        int ml = mf*16 + l4*4 + r;
        int cl = nf*16 + l15;
        float a = s[mf][nf][r] * inv[mf][r];
        arow[(long)(row0 + ml) * 1024 + (w*256 + cl)] = a;
        int byte = (ml*512 + cl*2) ^ ((ml & 7) << 4);
        *(unsigned short*)(pbase + byte) = f2bf(a);
      }
  __syncthreads();

  // ---- PV: wave-partial over its 256 keys; batched v-loads (MLP=8) ----
  f32x4 o[2][8];
  #pragma unroll
  for (int mf = 0; mf < 2; ++mf)
    #pragma unroll
    for (int df = 0; df < 8; ++df) o[mf][df] = (f32x4){0.f, 0.f, 0.f, 0.f};
  #pragma unroll
  for (int ks = 0; ks < 8; ++ks) {
    bf16x8 pa[2];
    #pragma unroll
    for (int mf = 0; mf < 2; ++mf) {
      int ml = mf*16 + l15;
      int byte = (ml*512 + (ks*32 + l4*8)*2) ^ ((ml & 7) << 4);
      pa[mf] = *(const bf16x8*)(pbase + byte);
    }
    bf16x8 vb[8];
    #pragma unroll
    for (int df = 0; df < 8; ++df) {
      long vi = base + (long)(ocol + df*16 + l15) * 1024 + (w*256 + ks*32 + l4*8);
      vb[df] = *(const bf16x8*)(vt + vi);
    }
    #pragma unroll
    for (int df = 0; df < 8; ++df)
      #pragma unroll
      for (int mf = 0; mf < 2; ++mf)
        o[mf][df] = __builtin_amdgcn_mfma_f32_16x16x32_bf16(pa[mf], vb[df], o[mf][df], 0, 0, 0);
  }
  __syncthreads();

  // ---- cross-wave reduce of PV partials ----
  float* pp = (float*)smem + w * 4096;   // [32][128] per wave
  #pragma unroll
  for (int mf = 0; mf < 2; ++mf)
    #pragma unroll
    for (int df = 0; df < 8; ++df)
      #pragma unroll
      for (int r = 0; r < 4; ++r)
        pp[(mf*16 + l4*4 + r)*128 + df*16 + l15] = o[mf][df][r];
  __syncthreads();
  #pragma unroll
  for (int it = 0; it < 4; ++it) {
    int i = tid + it*256;
    f32x4 a4 = ((const f32x4*)smem)[i];
    a4 += ((const f32x4*)(smem + 16384))[i];
    a4 += ((const f32x4*)(smem + 32768))[i];
    a4 += ((const f32x4*)(smem + 49152))[i];
    int ml = i >> 5, d0 = (i & 31) << 2;
    ushort4 stv;
    stv.x = f2bf(a4[0]); stv.y = f2bf(a4[1]); stv.z = f2bf(a4[2]); stv.w = f2bf(a4[3]);
    *(ushort4*)(outm + (long)(bb*1024 + row0 + ml) * 1024 + ocol + d0) = stv;
  }
}

// ---------------------------------------------------------------------------
// mask -> bit pack (1 bit per col)
// ---------------------------------------------------------------------------
__global__ __launch_bounds__(256) void pack_mask(const int* __restrict__ mask,
                                                 unsigned int* __restrict__ bits) {
  int w = threadIdx.x >> 6, l = threadIdx.x & 63;
  long rowid = (long)blockIdx.x * 4 + w;
  const int* mrow = mask + rowid * 1024;
  unsigned int* brow = bits + rowid * 32;
  #pragma unroll
  for (int it = 0; it < 16; ++it) {
    unsigned long long b = __ballot(mrow[it*64 + l] != 0);
    if (l == 0) { brow[it*2] = (unsigned int)b; brow[it*2 + 1] = (unsigned int)(b >> 32); }
  }
}

// ---------------------------------------------------------------------------
// LayerNorm over (d_model, seq) per batch: two-stage deterministic reduction.
// ---------------------------------------------------------------------------
__global__ __launch_bounds__(256) void ln_stats1(const float* __restrict__ x, float2* __restrict__ part) {
  __shared__ float2 sred[4];
  int b = blockIdx.y, blk = blockIdx.x;
  const float4* xp = (const float4*)(x + (long)b * 1048576 + (long)blk * 8192);
  float s = 0.f, ss = 0.f;
  for (int i = threadIdx.x; i < 2048; i += 256) {
    float4 v = xp[i];
    s  += v.x + v.y + v.z + v.w;
    ss += v.x*v.x + v.y*v.y + v.z*v.z + v.w*v.w;
  }
  #pragma unroll
  for (int o = 32; o; o >>= 1) { s += __shfl_down(s, o, 64); ss += __shfl_down(ss, o, 64); }
  if ((threadIdx.x & 63) == 0) sred[threadIdx.x >> 6] = make_float2(s, ss);
  __syncthreads();
  if (threadIdx.x == 0) {
    float S = 0.f, SS = 0.f;
    #pragma unroll
    for (int j = 0; j < 4; ++j) { S += sred[j].x; SS += sred[j].y; }
    part[b * 128 + blk] = make_float2(S, SS);
  }
}

__global__ __launch_bounds__(128) void ln_stats2(const float2* __restrict__ part, float2* __restrict__ stats,
                                                 float invN, float eps) {
  __shared__ float2 tmp[2];
  int b = blockIdx.x;
  float2 p = part[b * 128 + threadIdx.x];
  float s = p.x, ss = p.y;
  #pragma unroll
  for (int o = 32; o; o >>= 1) { s += __shfl_down(s, o, 64); ss += __shfl_down(ss, o, 64); }
  if ((threadIdx.x & 63) == 0) tmp[threadIdx.x >> 6] = make_float2(s, ss);
  __syncthreads();
  if (threadIdx.x == 0) {
    float S = tmp[0].x + tmp[1].x, SS = tmp[0].y + tmp[1].y;
    float mu = S * invN;
    float var = SS * invN - mu * mu;
    stats[b] = make_float2(mu, rsqrtf(var + eps));
  }
}

template<bool LO>
__global__ __launch_bounds__(256) void ln_apply(const float* __restrict__ x, const float* __restrict__ g,
                                                const float* __restrict__ be, const float2* __restrict__ stats,
                                                unsigned short* __restrict__ hi, unsigned short* __restrict__ lo) {
  long i = (long)blockIdx.x * 256 + threadIdx.x;
  long e = i << 2;
  int b   = (int)(e >> 20);
  int rem = (int)(e & 1048575);
  float2 st = stats[b];
  float4 xv = ((const float4*)x)[i];
  float4 gv = *(const float4*)(g + rem);
  float4 bv = *(const float4*)(be + rem);
  float h0 = (xv.x - st.x) * st.y * gv.x + bv.x;
  float h1 = (xv.y - st.x) * st.y * gv.y + bv.y;
  float h2 = (xv.z - st.x) * st.y * gv.z + bv.z;
  float h3 = (xv.w - st.x) * st.y * gv.w + bv.w;
  ushort4 h;
  h.x = f2bf(h0); h.y = f2bf(h1); h.z = f2bf(h2); h.w = f2bf(h3);
  ((ushort4*)hi)[i] = h;
  if (LO) {
    ushort4 l4;
    l4.x = f2bf(h0 - bf2f(h.x)); l4.y = f2bf(h1 - bf2f(h.y));
    l4.z = f2bf(h2 - bf2f(h.z)); l4.w = f2bf(h3 - bf2f(h.w));
    ((ushort4*)lo)[i] = l4;
  }
}

__global__ __launch_bounds__(256) void split_bf16(const float* __restrict__ src,
                                                  unsigned short* __restrict__ hi,
                                                  unsigned short* __restrict__ lo) {
  long i = (long)blockIdx.x * 256 + threadIdx.x;
  float4 v = ((const float4*)src)[i];
  ushort4 h, l4;
  h.x = f2bf(v.x); l4.x = f2bf(v.x - bf2f(h.x));
  h.y = f2bf(v.y); l4.y = f2bf(v.y - bf2f(h.y));
  h.z = f2bf(v.z); l4.z = f2bf(v.z - bf2f(h.z));
  h.w = f2bf(v.w); l4.w = f2bf(v.w - bf2f(h.w));
  ((ushort4*)hi)[i] = h;
  ((ushort4*)lo)[i] = l4;
}

__global__ __launch_bounds__(256) void cast_bf16(const float* __restrict__ src,
                                                 unsigned short* __restrict__ dst) {
  long i = (long)blockIdx.x * 256 + threadIdx.x;
  float4 v = ((const float4*)src)[i];
  ushort4 h;
  h.x = f2bf(v.x); h.y = f2bf(v.y); h.z = f2bf(v.z); h.w = f2bf(v.w);
  ((ushort4*)dst)[i] = h;
}

// k-head-norm from split bf16 k (hi+lo reconstruct), write split kn
__global__ __launch_bounds__(256) void knorm_split2(const unsigned short* __restrict__ k1,
                                                    const unsigned short* __restrict__ k2,
                                                    unsigned short* __restrict__ kn1,
                                                    unsigned short* __restrict__ kn2) {
  int t = blockIdx.x * 256 + threadIdx.x;
  int b = t >> 17;
  int rem = t & 131071;
  int m = rem >> 7;
  int d = rem & 127;
  long base = (long)b * 1048576 + (long)m * 1024 + d;
  float v[8]; float s = 0.f;
  #pragma unroll
  for (int h = 0; h < 8; ++h) {
    v[h] = bf2f(k1[base + h * 128]) + bf2f(k2[base + h * 128]);
    s += v[h] * v[h];
  }
  float rn = 1.f / fmaxf(sqrtf(s), 1e-12f);
  #pragma unroll
  for (int h = 0; h < 8; ++h) {
    float f = v[h] * rn;
    unsigned short hv = f2bf(f);
    kn1[base + h * 128] = hv;
    kn2[base + h * 128] = f2bf(f - bf2f(hv));
  }
}

// ---------------------------------------------------------------------------
extern "C" void kernel_launch(void* const* d_in, const int* in_sizes, int n_in,
                              void* d_out, int out_size, void* d_ws, size_t ws_size,
                              hipStream_t stream) {
  const float* enc  = (const float*)d_in[0];
  const int*   mask = (const int*)d_in[1];
  const float* ln1g = (const float*)d_in[2];
  const float* ln1b = (const float*)d_in[3];
  const float* wq   = (const float*)d_in[4];
  const float* wk   = (const float*)d_in[5];
  const float* wv   = (const float*)d_in[6];
  const float* wo   = (const float*)d_in[7];
  const float* ln2g = (const float*)d_in[8];
  const float* ln2b = (const float*)d_in[9];
  const float* w1   = (const float*)d_in[10];
  const float* b1   = (const float*)d_in[11];
  const float* w2   = (const float*)d_in[12];
  const float* b2   = (const float*)d_in[13];

  float* out_enc  = (float*)d_out;
  float* out_attn = out_enc + 8388608;   // [8, 8, 1024, 1024]

  const size_t MB = 1ull << 20;
  char* ws = (char*)d_ws;
  unsigned short* h1   = (unsigned short*)(ws + 0 * MB);     // LN1 hi  [8192,1024]
  unsigned short* h2   = (unsigned short*)(ws + 16 * MB);    // LN1 lo
  unsigned short* q1   = (unsigned short*)(ws + 32 * MB);    // q hi (later h2b)
  unsigned short* q2   = (unsigned short*)(ws + 48 * MB);    // q lo (later tb)
  unsigned short* k1r  = (unsigned short*)(ws + 64 * MB);    // k hi (raw)
  unsigned short* k2r  = (unsigned short*)(ws + 80 * MB);    // k lo (raw)
  unsigned short* kn1  = (unsigned short*)(ws + 96 * MB);    // k-normed hi
  unsigned short* kn2  = (unsigned short*)(ws + 112 * MB);   // k-normed lo
  unsigned short* vt   = (unsigned short*)(ws + 128 * MB);   // v^T per batch [b][o][m]
  unsigned short* outm = (unsigned short*)(ws + 144 * MB);   // attn@v merged [b][m][o]
  float*          x2f  = (float*)(ws + 160 * MB);            // attn-out + residual, f32
  unsigned short* h2b  = (unsigned short*)(ws + 32 * MB);    // LN2 out bf16 (reuse q1)
  unsigned short* tb   = (unsigned short*)(ws + 48 * MB);    // FFN1 out bf16 (reuse q2)
  unsigned short* wq1  = (unsigned short*)(ws + 192 * MB);
  unsigned short* wq2  = (unsigned short*)(ws + 194 * MB);
  unsigned short* wk1  = (unsigned short*)(ws + 196 * MB);
  unsigned short* wk2  = (unsigned short*)(ws + 198 * MB);
  unsigned short* wv1  = (unsigned short*)(ws + 200 * MB);
  unsigned short* wob  = (unsigned short*)(ws + 202 * MB);
  unsigned short* w1b  = (unsigned short*)(ws + 204 * MB);
  unsigned short* w2b  = (unsigned short*)(ws + 206 * MB);
  float2* part  = (float2*)(ws + 208 * MB);
  float2* stats = part + 1024;
  unsigned int* mbits = (unsigned int*)(ws + 209 * MB);      // 1 MB packed mask

  const float invN = 1.f / 1048576.f;

  // ---- LN1 + split ----
  ln_stats1<<<dim3(128, 8), 256, 0, stream>>>(enc, part);
  ln_stats2<<<dim3(8), 128, 0, stream>>>(part, stats, invN, 1e-6f);
  ln_apply<true><<<dim3(8192), 256, 0, stream>>>(enc, ln1g, ln1b, stats, h1, h2);

  // ---- weight casts + mask pack ----
  split_bf16<<<dim3(1024), 256, 0, stream>>>(wq, wq1, wq2);
  split_bf16<<<dim3(1024), 256, 0, stream>>>(wk, wk1, wk2);
  cast_bf16 <<<dim3(1024), 256, 0, stream>>>(wv, wv1);
  cast_bf16 <<<dim3(1024), 256, 0, stream>>>(wo, wob);
  cast_bf16 <<<dim3(1024), 256, 0, stream>>>(w1, w1b);
  cast_bf16 <<<dim3(1024), 256, 0, stream>>>(w2, w2b);
  pack_mask <<<dim3(2048), 256, 0, stream>>>(mask, mbits);

  // ---- q/k projections: fused split pass, split-bf16 output ----
  gemm_split<<<dim3(512), 256, 0, stream>>>(h1, h2, wq1, wq2, q1, q2, 8192, 1024, 1024, 1024, 1024, 1024);
  gemm_split<<<dim3(512), 256, 0, stream>>>(h1, h2, wk1, wk2, k1r, k2r, 8192, 1024, 1024, 1024, 1024, 1024);

  // ---- v projection -> v^T bf16 (per batch) ----
  gemm_bt<2><<<dim3(64, 1, 8), 256, 0, stream>>>(h1, wv1, vt, nullptr, nullptr,
      1024, 1024, 1024, 1024, 1024, 1024, 1, 1048576, 0, 0, 0, 1048576, 0);

  // ---- k head-norm + split ----
  knorm_split2<<<dim3(4096), 256, 0, stream>>>(k1r, k2r, kn1, kn2);

  // ---- fused attention: logits + mask + softmax + attn store + PV ----
  attn_fused<<<dim3(2048), 256, 0, stream>>>(q1, q2, kn1, kn2, vt, mbits, out_attn, outm);

  // ---- output projection + residual ----
  gemm_bt<3><<<dim3(512), 256, 0, stream>>>(outm, wob, x2f, nullptr, enc,
      8192, 1024, 1024, 1024, 1024, 1024, 1, 0, 0, 0, 0, 0, 0);

  // ---- LN2 ----
  ln_stats1<<<dim3(128, 8), 256, 0, stream>>>(x2f, part);
  ln_stats2<<<dim3(8), 128, 0, stream>>>(part, stats, invN, 1e-6f);
  ln_apply<false><<<dim3(8192), 256, 0, stream>>>(x2f, ln2g, ln2b, stats, h2b, nullptr);

  // ---- FFN ----
  gemm_bt<4><<<dim3(512), 256, 0, stream>>>(h2b, w1b, tb, b1, nullptr,
      8192, 1024, 1024, 1024, 1024, 1024, 1, 0, 0, 0, 0, 0, 0);
  gemm_bt<5><<<dim3(512), 256, 0, stream>>>(tb, w2b, out_enc, b2, x2f,
      8192, 1024, 1024, 1024, 1024, 1024, 1, 0, 0, 0, 0, 0, 0);
}